// Round 7
// baseline (157.646 us; speedup 1.0000x reference)
//
#include <hip/hip_runtime.h>
#include <math.h>

#define TSZ 2048
#define CDIM 1024

typedef __attribute__((ext_vector_type(8))) short s16x8;
typedef __attribute__((ext_vector_type(4))) float f32x4;
typedef __attribute__((ext_vector_type(16))) float f32x16;
typedef __attribute__((ext_vector_type(2))) unsigned int u32x2;
typedef __attribute__((ext_vector_type(4))) unsigned int u32x4;

#define QSCL 0.1803368801f   // log2(e) / sqrt(64), folded into Q at projection

__device__ __forceinline__ short f2bf(float f) {
    union { float f; unsigned u; } v; v.f = f;
    unsigned r = v.u + 0x7fffu + ((v.u >> 16) & 1u);   // RNE
    return (short)(r >> 16);
}
__device__ __forceinline__ unsigned cvtpk(float lo, float hi) {
    unsigned r;
    asm("v_cvt_pk_bf16_f32 %0, %1, %2" : "=v"(r) : "v"(lo), "v"(hi));
    return r;
}
__device__ __forceinline__ float fexp2(float x) {   // 2^x, single v_exp_f32
    float r;
    asm("v_exp_f32 %0, %1" : "=v"(r) : "v"(x));
    return r;
}
__device__ __forceinline__ s16x8 u2s(u32x4 u) {
    union { u32x4 u; s16x8 s; } c; c.u = u; return c.s;
}
__device__ __forceinline__ f32x16 mfma32(s16x8 a, s16x8 b, f32x16 c) {
    return __builtin_amdgcn_mfma_f32_32x32x16_bf16(a, b, c, 0, 0, 0);
}

// ---------------- fused casts: x + 5 weights in one launch ----------------
__global__ void cast_all(const float* __restrict__ x,
                         const float* __restrict__ w0, const float* __restrict__ w1,
                         const float* __restrict__ w2, const float* __restrict__ w3,
                         const float* __restrict__ w4,
                         short* __restrict__ xb,
                         short* __restrict__ o0, short* __restrict__ o1,
                         short* __restrict__ o2, short* __restrict__ o3,
                         short* __restrict__ o4) {
    int z = blockIdx.y;
    int i = blockIdx.x * blockDim.x + threadIdx.x;
    if (z == 0) {
        for (int j = i; j < (TSZ * 2 * CDIM) / 4; j += 1024 * 256) {
            float4 v = reinterpret_cast<const float4*>(x)[j];
            short4 o;
            o.x = f2bf(v.x); o.y = f2bf(v.y); o.z = f2bf(v.z); o.w = f2bf(v.w);
            reinterpret_cast<short4*>(xb)[j] = o;
        }
    } else {
        const float* s = z == 1 ? w0 : z == 2 ? w1 : z == 3 ? w2 : z == 4 ? w3 : w4;
        short* d = z == 1 ? o0 : z == 2 ? o1 : z == 3 ? o2 : z == 4 ? o3 : o4;
        float4 v = reinterpret_cast<const float4*>(s)[i];   // 1024*256 = CDIM*CDIM/4
        short4 o;
        o.x = f2bf(v.x); o.y = f2bf(v.y); o.z = f2bf(v.z); o.w = f2bf(v.w);
        reinterpret_cast<short4*>(d)[i] = o;
    }
}

// ---------------- LDS staging (global_load_lds, pre-swizzled source) ----------------
__device__ __forceinline__ void gload16(const short* g, short* l) {
    __builtin_amdgcn_global_load_lds((const __attribute__((address_space(1))) void*)g,
                                     (__attribute__((address_space(3))) void*)l, 16, 0, 0);
}

__device__ __forceinline__ void stage128x64(short* lds_t, const short* g, int ld, int tid, int w) {
    #pragma unroll
    for (int call = 0; call < 4; ++call) {
        int c = call * 256 + tid;
        int row = c >> 3;
        int sc = (c & 7) ^ (row & 7);
        gload16(g + (size_t)row * ld + sc * 8, lds_t + (size_t)(call * 256 + w * 64) * 8);
    }
}

__device__ __forceinline__ void stage64x64(short* lds_t, const short* g, int ld, int tid, int w) {
    #pragma unroll
    for (int call = 0; call < 2; ++call) {
        int c = call * 256 + tid;
        int row = c >> 3;
        int sc = (c & 7) ^ (row & 7);
        gload16(g + (size_t)row * ld + sc * 8, lds_t + (size_t)(call * 256 + w * 64) * 8);
    }
}

// read one MFMA fragment (8 bf16) from swizzled tile: row, 16B-chunk kc (0..7)
__device__ __forceinline__ s16x8 frag_read(const short* tile, int row, int kc) {
    const char* p = (const char*)tile + row * 128 + (((kc ^ (row & 7)) & 7) << 4);
    return *reinterpret_cast<const s16x8*>(p);
}

// ---------------- projection GEMM: C = A(4096x1024) * W^T, 4 weights ----------------
// z==0 (Q) output is pre-scaled by log2(e)/sqrt(D) so attention exp is a bare v_exp_f32.
__global__ __launch_bounds__(256) void gemm4_proj(
    const short* __restrict__ xb,
    const short* __restrict__ w0, const short* __restrict__ w1,
    const short* __restrict__ w2, const short* __restrict__ w3,
    short* __restrict__ o0, short* __restrict__ o1,
    short* __restrict__ o2, short* __restrict__ o3)
{
    __shared__ short sA[128 * 64], sB[128 * 64];
    int tid = threadIdx.x, lane = tid & 63, w = tid >> 6;
    int wrow = w >> 1, wcol = w & 1;
    int z = blockIdx.y;
    const short* W = z == 0 ? w0 : z == 1 ? w1 : z == 2 ? w2 : w3;
    short* outp = z == 0 ? o0 : z == 1 ? o1 : z == 2 ? o2 : o3;
    int bx = blockIdx.x;
    bx = (bx & 7) * 32 + (bx >> 3);          // XCD-chunked swizzle (256 = 8*32)
    int r0 = (bx >> 3) * 128;
    int c0 = (bx & 7) * 128;

    f32x4 zero = {0.f, 0.f, 0.f, 0.f};
    f32x4 acc[4][4];
    #pragma unroll
    for (int i = 0; i < 4; ++i)
        #pragma unroll
        for (int j = 0; j < 4; ++j) acc[i][j] = zero;

    for (int kt = 0; kt < 16; ++kt) {
        __syncthreads();
        stage128x64(sA, xb + (size_t)r0 * CDIM + kt * 64, CDIM, tid, w);
        stage128x64(sB, W + (size_t)c0 * CDIM + kt * 64, CDIM, tid, w);
        __syncthreads();
        #pragma unroll
        for (int ks = 0; ks < 2; ++ks) {
            int kc = ks * 4 + (lane >> 4);
            s16x8 af[4], bfr[4];
            #pragma unroll
            for (int mt = 0; mt < 4; ++mt) af[mt] = frag_read(sA, wrow * 64 + mt * 16 + (lane & 15), kc);
            #pragma unroll
            for (int nt = 0; nt < 4; ++nt) bfr[nt] = frag_read(sB, wcol * 64 + nt * 16 + (lane & 15), kc);
            #pragma unroll
            for (int mt = 0; mt < 4; ++mt)
                #pragma unroll
                for (int nt = 0; nt < 4; ++nt)
                    acc[mt][nt] = __builtin_amdgcn_mfma_f32_16x16x32_bf16(af[mt], bfr[nt], acc[mt][nt], 0, 0, 0);
        }
    }

    bool vt_mode = (z == 2);
    float oscale = (z == 0) ? QSCL : 1.0f;
    #pragma unroll
    for (int mt = 0; mt < 4; ++mt)
        #pragma unroll
        for (int nt = 0; nt < 4; ++nt)
            #pragma unroll
            for (int jr = 0; jr < 4; ++jr) {
                int gi = r0 + wrow * 64 + mt * 16 + ((lane >> 4) << 2) + jr;
                int gn = c0 + wcol * 64 + nt * 16 + (lane & 15);
                short v = f2bf(acc[mt][nt][jr] * oscale);
                int b = gi >> 11, t = gi & 2047, h = gn >> 6, d = gn & 63;
                size_t off;
                if (!vt_mode) off = ((size_t)(b * 16 + h) * TSZ + t) * 64 + d;   // (B,H,T,D)
                else          off = ((size_t)(b * 16 + h) * 64 + d) * TSZ + t;   // (B,H,D,T)
                outp[off] = v;
            }
}

// ---------------- final GEMM: out(f32) = attn(4096x1024 bf16) * Wo^T ----------------
__global__ __launch_bounds__(256) void gemm_final(
    const short* __restrict__ ab, const short* __restrict__ wo, float* __restrict__ out)
{
    __shared__ short sA[128 * 64], sB[128 * 64];
    int tid = threadIdx.x, lane = tid & 63, w = tid >> 6;
    int wrow = w >> 1, wcol = w & 1;
    int bx = blockIdx.x;
    bx = (bx & 7) * 32 + (bx >> 3);          // XCD-chunked swizzle
    int r0 = (bx >> 3) * 128;
    int c0 = (bx & 7) * 128;

    f32x4 zero = {0.f, 0.f, 0.f, 0.f};
    f32x4 acc[4][4];
    #pragma unroll
    for (int i = 0; i < 4; ++i)
        #pragma unroll
        for (int j = 0; j < 4; ++j) acc[i][j] = zero;

    for (int kt = 0; kt < 16; ++kt) {
        __syncthreads();
        stage128x64(sA, ab + (size_t)r0 * CDIM + kt * 64, CDIM, tid, w);
        stage128x64(sB, wo + (size_t)c0 * CDIM + kt * 64, CDIM, tid, w);
        __syncthreads();
        #pragma unroll
        for (int ks = 0; ks < 2; ++ks) {
            int kc = ks * 4 + (lane >> 4);
            s16x8 af[4], bfr[4];
            #pragma unroll
            for (int mt = 0; mt < 4; ++mt) af[mt] = frag_read(sA, wrow * 64 + mt * 16 + (lane & 15), kc);
            #pragma unroll
            for (int nt = 0; nt < 4; ++nt) bfr[nt] = frag_read(sB, wcol * 64 + nt * 16 + (lane & 15), kc);
            #pragma unroll
            for (int mt = 0; mt < 4; ++mt)
                #pragma unroll
                for (int nt = 0; nt < 4; ++nt)
                    acc[mt][nt] = __builtin_amdgcn_mfma_f32_16x16x32_bf16(af[mt], bfr[nt], acc[mt][nt], 0, 0, 0);
        }
    }

    #pragma unroll
    for (int mt = 0; mt < 4; ++mt)
        #pragma unroll
        for (int nt = 0; nt < 4; ++nt)
            #pragma unroll
            for (int jr = 0; jr < 4; ++jr) {
                int gi = r0 + wrow * 64 + mt * 16 + ((lane >> 4) << 2) + jr;
                int gn = c0 + wcol * 64 + nt * 16 + (lane & 15);
                out[(size_t)gi * CDIM + gn] = acc[mt][nt][jr];
            }
}

// ---------------- fused dual-branch flash attention: branch-per-wave + 3-deep pipe ----
// Wave w: qg = w>>1 (64 q-rows), br = w&1 (branch). Fixed m=0 softmax (validated
// r4/r5), Q pre-scaled so exp = bare v_exp_f32. K/K'/V triple-buffered (T3/T4):
// counted s_waitcnt vmcnt(6) + raw s_barrier per iter -- tile t+1's loads stay in
// flight across the barrier (never drain to 0 in the main loop).
__global__ __launch_bounds__(256, 2) void attn_fused(
    const short* __restrict__ q, const short* __restrict__ k, const short* __restrict__ kp,
    const short* __restrict__ vt, const float* __restrict__ alphap, short* __restrict__ aout)
{
    __shared__ short sbuf[9][64 * 64];   // [0..2]=K 3buf, [3..5]=K' 3buf, [6..8]=V 3buf
    int tid = threadIdx.x, lane = tid & 63, w = tid >> 6;
    int h = lane >> 5, l31 = lane & 31;
    int qg = w >> 1, br = w & 1;

    int id = blockIdx.x + gridDim.x * blockIdx.y;     // 512 blocks
    int nid = (id & 7) * 64 + (id >> 3);              // XCD-chunked (512 = 8*64)
    int bh = nid >> 4;
    int qt0 = (nid & 15) * 128;

    const short* Q   = q  + (size_t)bh * TSZ * 64;
    const short* Kg  = k  + (size_t)bh * TSZ * 64;
    const short* Kpg = kp + (size_t)bh * TSZ * 64;
    const short* Vt  = vt + (size_t)bh * 64 * TSZ;

    // Q frags for this wave's two 32-q subtiles
    s16x8 qf[2][4];
    #pragma unroll
    for (int qb = 0; qb < 2; ++qb)
        #pragma unroll
        for (int s = 0; s < 4; ++s)
            qf[qb][s] = *reinterpret_cast<const s16x8*>(
                Q + (size_t)(qt0 + qg * 64 + qb * 32 + l31) * 64 + s * 16 + h * 8);

    f32x16 o[2][2];
    #pragma unroll
    for (int qb = 0; qb < 2; ++qb)
        #pragma unroll
        for (int dt = 0; dt < 2; ++dt)
            #pragma unroll
            for (int r = 0; r < 16; ++r) o[qb][dt][r] = 0.f;
    float lloc[2] = {0.f, 0.f};

    // pin Q-loads before staging so the vmcnt ledger below is exact
    __builtin_amdgcn_sched_barrier(0);

    // prologue: stage tiles 0 and 1 (6 loads/thread each -> 12 outstanding)
    stage64x64(sbuf[0], Kg,  64, tid, w);
    stage64x64(sbuf[3], Kpg, 64, tid, w);
    stage64x64(sbuf[6], Vt,  TSZ, tid, w);
    stage64x64(sbuf[1], Kg  + 64 * 64, 64, tid, w);
    stage64x64(sbuf[4], Kpg + 64 * 64, 64, tid, w);
    stage64x64(sbuf[7], Vt + 64, TSZ, tid, w);

    for (int kt = 0; kt < 32; ++kt) {
        // counted wait: tile kt done, tile kt+1's 6 loads may stay in flight
        if (kt < 31) asm volatile("s_waitcnt vmcnt(6)" ::: "memory");
        else         asm volatile("s_waitcnt vmcnt(0)" ::: "memory");
        __builtin_amdgcn_s_barrier();
        __builtin_amdgcn_sched_barrier(0);

        // issue tile kt+2 (overwrites buffer last read at iter kt-1; safe past barrier)
        if (kt < 30) {
            int t0n = (kt + 2) * 64;
            int sl = (kt + 2) % 3;
            stage64x64(sbuf[sl],     Kg  + (size_t)t0n * 64, 64, tid, w);
            stage64x64(sbuf[3 + sl], Kpg + (size_t)t0n * 64, 64, tid, w);
            stage64x64(sbuf[6 + sl], Vt + t0n, TSZ, tid, w);
        }
        int cur = kt % 3;
        const short* kbuf = br ? sbuf[3 + cur] : sbuf[cur];
        const short* vbuf = sbuf[6 + cur];

        // QK^T for both q-subtiles; each K-frag read feeds 2 MFMAs
        f32x16 sa[2][2];
        #pragma unroll
        for (int qb = 0; qb < 2; ++qb)
            #pragma unroll
            for (int hf = 0; hf < 2; ++hf)
                #pragma unroll
                for (int r = 0; r < 16; ++r) sa[qb][hf][r] = 0.f;
        __builtin_amdgcn_s_setprio(1);
        #pragma unroll
        for (int s = 0; s < 4; ++s) {
            s16x8 af0 = frag_read(kbuf, l31,      2 * s + h);
            s16x8 af1 = frag_read(kbuf, 32 + l31, 2 * s + h);
            sa[0][0] = mfma32(af0, qf[0][s], sa[0][0]);
            sa[0][1] = mfma32(af1, qf[0][s], sa[0][1]);
            sa[1][0] = mfma32(af0, qf[1][s], sa[1][0]);
            sa[1][1] = mfma32(af1, qf[1][s], sa[1][1]);
        }
        __builtin_amdgcn_s_setprio(0);

        u32x4 pfrag[2][4];
        #pragma unroll
        for (int qb = 0; qb < 2; ++qb) {
            // fixed-m softmax: p = 2^S' (Q pre-scaled); 4-way partial sums
            float p0 = 0.f, p1 = 0.f, p2 = 0.f, p3 = 0.f;
            #pragma unroll
            for (int r = 0; r < 16; r += 4) {
                sa[qb][0][r]     = fexp2(sa[qb][0][r]);     p0 += sa[qb][0][r];
                sa[qb][0][r + 1] = fexp2(sa[qb][0][r + 1]); p1 += sa[qb][0][r + 1];
                sa[qb][0][r + 2] = fexp2(sa[qb][0][r + 2]); p2 += sa[qb][0][r + 2];
                sa[qb][0][r + 3] = fexp2(sa[qb][0][r + 3]); p3 += sa[qb][0][r + 3];
                sa[qb][1][r]     = fexp2(sa[qb][1][r]);     p0 += sa[qb][1][r];
                sa[qb][1][r + 1] = fexp2(sa[qb][1][r + 1]); p1 += sa[qb][1][r + 1];
                sa[qb][1][r + 2] = fexp2(sa[qb][1][r + 2]); p2 += sa[qb][1][r + 2];
                sa[qb][1][r + 3] = fexp2(sa[qb][1][r + 3]); p3 += sa[qb][1][r + 3];
            }
            lloc[qb] += (p0 + p1) + (p2 + p3);

            // pack P -> bf16 B-frags: cvt_pk + permlane32_swap (T12)
            #pragma unroll
            for (int t = 0; t < 2; ++t) {
                unsigned pk[8];
                #pragma unroll
                for (int i = 0; i < 8; ++i)
                    pk[i] = cvtpk(sa[qb][t][2 * i], sa[qb][t][2 * i + 1]);
                u32x2 r02 = __builtin_amdgcn_permlane32_swap(pk[0], pk[2], false, false);
                u32x2 r13 = __builtin_amdgcn_permlane32_swap(pk[1], pk[3], false, false);
                u32x2 r46 = __builtin_amdgcn_permlane32_swap(pk[4], pk[6], false, false);
                u32x2 r57 = __builtin_amdgcn_permlane32_swap(pk[5], pk[7], false, false);
                u32x4 fA, fB;
                fA[0] = r02[0]; fA[1] = r13[0]; fA[2] = r02[1]; fA[3] = r13[1];
                fB[0] = r46[0]; fB[1] = r57[0]; fB[2] = r46[1]; fB[3] = r57[1];
                pfrag[qb][2 * t] = fA;
                pfrag[qb][2 * t + 1] = fB;
            }
        }

        // PV: each V-frag read feeds both q-subtiles
        __builtin_amdgcn_s_setprio(1);
        #pragma unroll
        for (int s = 0; s < 4; ++s)
            #pragma unroll
            for (int dt = 0; dt < 2; ++dt) {
                s16x8 vf = frag_read(vbuf, dt * 32 + l31, 2 * s + h);
                o[0][dt] = mfma32(vf, u2s(pfrag[0][s]), o[0][dt]);
                o[1][dt] = mfma32(vf, u2s(pfrag[1][s]), o[1][dt]);
            }
        __builtin_amdgcn_s_setprio(0);
    }

    __syncthreads();   // all compute done before sbuf is reused as exchange scratch

    // epilogue: scale own branch, exchange br=1 partials via LDS, combine, store
    float alpha = alphap[0];
    float cb = br ? (1.f - alpha) : alpha;
    float inv[2];
    #pragma unroll
    for (int qb = 0; qb < 2; ++qb) {
        float ls = lloc[qb] + __shfl_xor(lloc[qb], 32, 64);
        inv[qb] = cb / ls;
    }

    float* sX = (float*)&sbuf[0][0];   // 32KB of the 72KB LDS, free after last barrier
    if (br) {
        #pragma unroll
        for (int qb = 0; qb < 2; ++qb)
            #pragma unroll
            for (int dt = 0; dt < 2; ++dt)
                #pragma unroll
                for (int g = 0; g < 4; ++g) {
                    int qloc = qg * 64 + qb * 32 + l31;
                    int dsw = (dt * 32 + g * 8 + h * 4) ^ ((l31 & 7) << 3);
                    float4 v4;
                    v4.x = o[qb][dt][4 * g + 0] * inv[qb];
                    v4.y = o[qb][dt][4 * g + 1] * inv[qb];
                    v4.z = o[qb][dt][4 * g + 2] * inv[qb];
                    v4.w = o[qb][dt][4 * g + 3] * inv[qb];
                    *reinterpret_cast<float4*>(sX + qloc * 64 + dsw) = v4;
                }
    }
    __syncthreads();
    if (!br) {
        int b = bh >> 4, hh = bh & 15;
        #pragma unroll
        for (int qb = 0; qb < 2; ++qb) {
            int t = qt0 + qg * 64 + qb * 32 + l31;
            size_t rowbase = ((size_t)(b * TSZ + t)) * CDIM + hh * 64;
            #pragma unroll
            for (int dt = 0; dt < 2; ++dt)
                #pragma unroll
                for (int g = 0; g < 4; ++g) {
                    int qloc = qg * 64 + qb * 32 + l31;
                    int dsw = (dt * 32 + g * 8 + h * 4) ^ ((l31 & 7) << 3);
                    float4 p = *reinterpret_cast<const float4*>(sX + qloc * 64 + dsw);
                    short4 v4;
                    v4.x = f2bf(o[qb][dt][4 * g + 0] * inv[qb] + p.x);
                    v4.y = f2bf(o[qb][dt][4 * g + 1] * inv[qb] + p.y);
                    v4.z = f2bf(o[qb][dt][4 * g + 2] * inv[qb] + p.z);
                    v4.w = f2bf(o[qb][dt][4 * g + 3] * inv[qb] + p.w);
                    *reinterpret_cast<short4*>(aout + rowbase + dt * 32 + g * 8 + h * 4) = v4;
                }
        }
    }
}

// ---------------- host ----------------
extern "C" void kernel_launch(void* const* d_in, const int* in_sizes, int n_in,
                              void* d_out, int out_size, void* d_ws, size_t ws_size,
                              hipStream_t stream)
{
    const float* x     = (const float*)d_in[0];
    const float* WQ    = (const float*)d_in[1];
    const float* WK    = (const float*)d_in[2];
    const float* WV    = (const float*)d_in[3];
    const float* WKp   = (const float*)d_in[4];
    const float* WO    = (const float*)d_in[5];
    const float* alpha = (const float*)d_in[6];
    float* out = (float*)d_out;

    char* ws = (char*)d_ws;
    const size_t MB = 1024 * 1024;
    short* xb   = (short*)(ws + 0);        // 8 MB  x bf16
    short* wqb  = (short*)(ws + 8 * MB);   // 2 MB each
    short* wkb  = (short*)(ws + 10 * MB);
    short* wvb  = (short*)(ws + 12 * MB);
    short* wkpb = (short*)(ws + 14 * MB);
    short* wob  = (short*)(ws + 16 * MB);
    short* qb   = (short*)(ws + 18 * MB);  // 8 MB each, (B,H,T,D)
    short* kb   = (short*)(ws + 26 * MB);
    short* kpb  = (short*)(ws + 34 * MB);
    short* vtb  = (short*)(ws + 42 * MB);  // (B,H,D,T)
    short* anb  = (short*)(ws + 50 * MB);  // attention out, (B,T,C) bf16

    cast_all<<<dim3(1024, 6), 256, 0, stream>>>(x, WQ, WK, WV, WKp, WO,
                                                xb, wqb, wkb, wvb, wkpb, wob);

    gemm4_proj<<<dim3(256, 4), 256, 0, stream>>>(xb, wqb, wkb, wvb, wkpb, qb, kb, vtb, kpb);
    attn_fused<<<dim3(16, 32), 256, 0, stream>>>(qb, kb, kpb, vtb, alpha, anb);
    gemm_final<<<dim3(256), 256, 0, stream>>>(anb, wob, out);
}

// Round 11
// 156.803 us; speedup vs baseline: 1.0054x; 1.0054x over previous
//
#include <hip/hip_runtime.h>
#include <math.h>

#define TSZ 2048
#define CDIM 1024

typedef __attribute__((ext_vector_type(8))) short s16x8;
typedef __attribute__((ext_vector_type(4))) float f32x4;
typedef __attribute__((ext_vector_type(16))) float f32x16;
typedef __attribute__((ext_vector_type(2))) unsigned int u32x2;
typedef __attribute__((ext_vector_type(4))) unsigned int u32x4;

#define QSCL 0.1803368801f   // log2(e) / sqrt(64), folded into Q at projection

__device__ __forceinline__ short f2bf(float f) {
    union { float f; unsigned u; } v; v.f = f;
    unsigned r = v.u + 0x7fffu + ((v.u >> 16) & 1u);   // RNE
    return (short)(r >> 16);
}
__device__ __forceinline__ unsigned cvtpk(float lo, float hi) {
    unsigned r;
    asm("v_cvt_pk_bf16_f32 %0, %1, %2" : "=v"(r) : "v"(lo), "v"(hi));
    return r;
}
__device__ __forceinline__ float fexp2(float x) {   // 2^x, single v_exp_f32
    float r;
    asm("v_exp_f32 %0, %1" : "=v"(r) : "v"(x));
    return r;
}
__device__ __forceinline__ s16x8 u2s(u32x4 u) {
    union { u32x4 u; s16x8 s; } c; c.u = u; return c.s;
}
__device__ __forceinline__ f32x16 mfma32(s16x8 a, s16x8 b, f32x16 c) {
    return __builtin_amdgcn_mfma_f32_32x32x16_bf16(a, b, c, 0, 0, 0);
}

// ---------------- fused casts: x + 5 weights in one launch ----------------
__global__ void cast_all(const float* __restrict__ x,
                         const float* __restrict__ w0, const float* __restrict__ w1,
                         const float* __restrict__ w2, const float* __restrict__ w3,
                         const float* __restrict__ w4,
                         short* __restrict__ xb,
                         short* __restrict__ o0, short* __restrict__ o1,
                         short* __restrict__ o2, short* __restrict__ o3,
                         short* __restrict__ o4) {
    int z = blockIdx.y;
    int i = blockIdx.x * blockDim.x + threadIdx.x;
    if (z == 0) {
        for (int j = i; j < (TSZ * 2 * CDIM) / 4; j += 1024 * 256) {
            float4 v = reinterpret_cast<const float4*>(x)[j];
            short4 o;
            o.x = f2bf(v.x); o.y = f2bf(v.y); o.z = f2bf(v.z); o.w = f2bf(v.w);
            reinterpret_cast<short4*>(xb)[j] = o;
        }
    } else {
        const float* s = z == 1 ? w0 : z == 2 ? w1 : z == 3 ? w2 : z == 4 ? w3 : w4;
        short* d = z == 1 ? o0 : z == 2 ? o1 : z == 3 ? o2 : z == 4 ? o3 : o4;
        float4 v = reinterpret_cast<const float4*>(s)[i];   // 1024*256 = CDIM*CDIM/4
        short4 o;
        o.x = f2bf(v.x); o.y = f2bf(v.y); o.z = f2bf(v.z); o.w = f2bf(v.w);
        reinterpret_cast<short4*>(d)[i] = o;
    }
}

// ---------------- LDS staging (global_load_lds, pre-swizzled source) ----------------
__device__ __forceinline__ void gload16(const short* g, short* l) {
    __builtin_amdgcn_global_load_lds((const __attribute__((address_space(1))) void*)g,
                                     (__attribute__((address_space(3))) void*)l, 16, 0, 0);
}

__device__ __forceinline__ void stage128x64(short* lds_t, const short* g, int ld, int tid, int w) {
    #pragma unroll
    for (int call = 0; call < 4; ++call) {
        int c = call * 256 + tid;
        int row = c >> 3;
        int sc = (c & 7) ^ (row & 7);
        gload16(g + (size_t)row * ld + sc * 8, lds_t + (size_t)(call * 256 + w * 64) * 8);
    }
}

__device__ __forceinline__ void stage64x64(short* lds_t, const short* g, int ld, int tid, int w) {
    #pragma unroll
    for (int call = 0; call < 2; ++call) {
        int c = call * 256 + tid;
        int row = c >> 3;
        int sc = (c & 7) ^ (row & 7);
        gload16(g + (size_t)row * ld + sc * 8, lds_t + (size_t)(call * 256 + w * 64) * 8);
    }
}

// read one MFMA fragment (8 bf16) from swizzled tile: row, 16B-chunk kc (0..7)
__device__ __forceinline__ s16x8 frag_read(const short* tile, int row, int kc) {
    const char* p = (const char*)tile + row * 128 + (((kc ^ (row & 7)) & 7) << 4);
    return *reinterpret_cast<const s16x8*>(p);
}

// ---------------- projection GEMM: C = A(4096x1024) * W^T, 4 weights ----------------
// z==0 (Q) output is pre-scaled by log2(e)/sqrt(D) so attention exp is a bare v_exp_f32.
__global__ __launch_bounds__(256) void gemm4_proj(
    const short* __restrict__ xb,
    const short* __restrict__ w0, const short* __restrict__ w1,
    const short* __restrict__ w2, const short* __restrict__ w3,
    short* __restrict__ o0, short* __restrict__ o1,
    short* __restrict__ o2, short* __restrict__ o3)
{
    __shared__ short sA[128 * 64], sB[128 * 64];
    int tid = threadIdx.x, lane = tid & 63, w = tid >> 6;
    int wrow = w >> 1, wcol = w & 1;
    int z = blockIdx.y;
    const short* W = z == 0 ? w0 : z == 1 ? w1 : z == 2 ? w2 : w3;
    short* outp = z == 0 ? o0 : z == 1 ? o1 : z == 2 ? o2 : o3;
    int bx = blockIdx.x;
    bx = (bx & 7) * 32 + (bx >> 3);          // XCD-chunked swizzle (256 = 8*32)
    int r0 = (bx >> 3) * 128;
    int c0 = (bx & 7) * 128;

    f32x4 zero = {0.f, 0.f, 0.f, 0.f};
    f32x4 acc[4][4];
    #pragma unroll
    for (int i = 0; i < 4; ++i)
        #pragma unroll
        for (int j = 0; j < 4; ++j) acc[i][j] = zero;

    for (int kt = 0; kt < 16; ++kt) {
        __syncthreads();
        stage128x64(sA, xb + (size_t)r0 * CDIM + kt * 64, CDIM, tid, w);
        stage128x64(sB, W + (size_t)c0 * CDIM + kt * 64, CDIM, tid, w);
        __syncthreads();
        #pragma unroll
        for (int ks = 0; ks < 2; ++ks) {
            int kc = ks * 4 + (lane >> 4);
            s16x8 af[4], bfr[4];
            #pragma unroll
            for (int mt = 0; mt < 4; ++mt) af[mt] = frag_read(sA, wrow * 64 + mt * 16 + (lane & 15), kc);
            #pragma unroll
            for (int nt = 0; nt < 4; ++nt) bfr[nt] = frag_read(sB, wcol * 64 + nt * 16 + (lane & 15), kc);
            #pragma unroll
            for (int mt = 0; mt < 4; ++mt)
                #pragma unroll
                for (int nt = 0; nt < 4; ++nt)
                    acc[mt][nt] = __builtin_amdgcn_mfma_f32_16x16x32_bf16(af[mt], bfr[nt], acc[mt][nt], 0, 0, 0);
        }
    }

    bool vt_mode = (z == 2);
    float oscale = (z == 0) ? QSCL : 1.0f;
    #pragma unroll
    for (int mt = 0; mt < 4; ++mt)
        #pragma unroll
        for (int nt = 0; nt < 4; ++nt)
            #pragma unroll
            for (int jr = 0; jr < 4; ++jr) {
                int gi = r0 + wrow * 64 + mt * 16 + ((lane >> 4) << 2) + jr;
                int gn = c0 + wcol * 64 + nt * 16 + (lane & 15);
                short v = f2bf(acc[mt][nt][jr] * oscale);
                int b = gi >> 11, t = gi & 2047, h = gn >> 6, d = gn & 63;
                size_t off;
                if (!vt_mode) off = ((size_t)(b * 16 + h) * TSZ + t) * 64 + d;   // (B,H,T,D)
                else          off = ((size_t)(b * 16 + h) * 64 + d) * TSZ + t;   // (B,H,D,T)
                outp[off] = v;
            }
}

// ---------------- final GEMM: out(f32) = attn(4096x1024 bf16) * Wo^T ----------------
__global__ __launch_bounds__(256) void gemm_final(
    const short* __restrict__ ab, const short* __restrict__ wo, float* __restrict__ out)
{
    __shared__ short sA[128 * 64], sB[128 * 64];
    int tid = threadIdx.x, lane = tid & 63, w = tid >> 6;
    int wrow = w >> 1, wcol = w & 1;
    int bx = blockIdx.x;
    bx = (bx & 7) * 32 + (bx >> 3);          // XCD-chunked swizzle
    int r0 = (bx >> 3) * 128;
    int c0 = (bx & 7) * 128;

    f32x4 zero = {0.f, 0.f, 0.f, 0.f};
    f32x4 acc[4][4];
    #pragma unroll
    for (int i = 0; i < 4; ++i)
        #pragma unroll
        for (int j = 0; j < 4; ++j) acc[i][j] = zero;

    for (int kt = 0; kt < 16; ++kt) {
        __syncthreads();
        stage128x64(sA, ab + (size_t)r0 * CDIM + kt * 64, CDIM, tid, w);
        stage128x64(sB, wo + (size_t)c0 * CDIM + kt * 64, CDIM, tid, w);
        __syncthreads();
        #pragma unroll
        for (int ks = 0; ks < 2; ++ks) {
            int kc = ks * 4 + (lane >> 4);
            s16x8 af[4], bfr[4];
            #pragma unroll
            for (int mt = 0; mt < 4; ++mt) af[mt] = frag_read(sA, wrow * 64 + mt * 16 + (lane & 15), kc);
            #pragma unroll
            for (int nt = 0; nt < 4; ++nt) bfr[nt] = frag_read(sB, wcol * 64 + nt * 16 + (lane & 15), kc);
            #pragma unroll
            for (int mt = 0; mt < 4; ++mt)
                #pragma unroll
                for (int nt = 0; nt < 4; ++nt)
                    acc[mt][nt] = __builtin_amdgcn_mfma_f32_16x16x32_bf16(af[mt], bfr[nt], acc[mt][nt], 0, 0, 0);
        }
    }

    #pragma unroll
    for (int mt = 0; mt < 4; ++mt)
        #pragma unroll
        for (int nt = 0; nt < 4; ++nt)
            #pragma unroll
            for (int jr = 0; jr < 4; ++jr) {
                int gi = r0 + wrow * 64 + mt * 16 + ((lane >> 4) << 2) + jr;
                int gn = c0 + wcol * 64 + nt * 16 + (lane & 15);
                out[(size_t)gi * CDIM + gn] = acc[mt][nt][jr];
            }
}

// ---------------- fused dual-branch flash attention: branch-per-wave, 64q/wave ----
// PROVEN round-6 kernel (verbatim). Wave w: qg = w>>1 (q-subrange), br = w&1
// (branch). Each wave computes ONE branch for 64 q-rows (2 subtiles of 32).
// Fixed m=0 softmax (validated r4/r5), Q pre-scaled so exp = bare v_exp_f32.
// Branch combine via one-time LDS exchange.
__global__ __launch_bounds__(256, 2) void attn_fused(
    const short* __restrict__ q, const short* __restrict__ k, const short* __restrict__ kp,
    const short* __restrict__ vt, const float* __restrict__ alphap, short* __restrict__ aout)
{
    __shared__ short sbuf[6][64 * 64];   // [0,1]=K dbuf, [2,3]=K' dbuf, [4,5]=V dbuf
    int tid = threadIdx.x, lane = tid & 63, w = tid >> 6;
    int h = lane >> 5, l31 = lane & 31;
    int qg = w >> 1, br = w & 1;

    int id = blockIdx.x + gridDim.x * blockIdx.y;     // 512 blocks
    int nid = (id & 7) * 64 + (id >> 3);              // XCD-chunked (512 = 8*64)
    int bh = nid >> 4;
    int qt0 = (nid & 15) * 128;

    const short* Q   = q  + (size_t)bh * TSZ * 64;
    const short* Kg  = k  + (size_t)bh * TSZ * 64;
    const short* Kpg = kp + (size_t)bh * TSZ * 64;
    const short* Vt  = vt + (size_t)bh * 64 * TSZ;

    // Q frags for this wave's two 32-q subtiles
    s16x8 qf[2][4];
    #pragma unroll
    for (int qb = 0; qb < 2; ++qb)
        #pragma unroll
        for (int s = 0; s < 4; ++s)
            qf[qb][s] = *reinterpret_cast<const s16x8*>(
                Q + (size_t)(qt0 + qg * 64 + qb * 32 + l31) * 64 + s * 16 + h * 8);

    f32x16 o[2][2];
    #pragma unroll
    for (int qb = 0; qb < 2; ++qb)
        #pragma unroll
        for (int dt = 0; dt < 2; ++dt)
            #pragma unroll
            for (int r = 0; r < 16; ++r) o[qb][dt][r] = 0.f;
    float lloc[2] = {0.f, 0.f};

    // prologue: all waves cooperatively stage tile 0 (K, K', V)
    stage64x64(sbuf[0], Kg, 64, tid, w);
    stage64x64(sbuf[2], Kpg, 64, tid, w);
    stage64x64(sbuf[4], Vt, TSZ, tid, w);
    __syncthreads();

    int cur = 0;
    for (int kt = 0; kt < 32; ++kt) {
        if (kt < 31) {
            int t0n = (kt + 1) * 64;
            stage64x64(sbuf[cur ^ 1],       Kg  + (size_t)t0n * 64, 64, tid, w);
            stage64x64(sbuf[2 + (cur ^ 1)], Kpg + (size_t)t0n * 64, 64, tid, w);
            stage64x64(sbuf[4 + (cur ^ 1)], Vt + t0n, TSZ, tid, w);
        }
        const short* kbuf = br ? sbuf[2 + cur] : sbuf[cur];
        const short* vbuf = sbuf[4 + cur];

        // QK^T for both q-subtiles; each K-frag read feeds 2 MFMAs
        f32x16 sa[2][2];
        #pragma unroll
        for (int qb = 0; qb < 2; ++qb)
            #pragma unroll
            for (int hf = 0; hf < 2; ++hf)
                #pragma unroll
                for (int r = 0; r < 16; ++r) sa[qb][hf][r] = 0.f;
        __builtin_amdgcn_s_setprio(1);
        #pragma unroll
        for (int s = 0; s < 4; ++s) {
            s16x8 af0 = frag_read(kbuf, l31,      2 * s + h);
            s16x8 af1 = frag_read(kbuf, 32 + l31, 2 * s + h);
            sa[0][0] = mfma32(af0, qf[0][s], sa[0][0]);
            sa[0][1] = mfma32(af1, qf[0][s], sa[0][1]);
            sa[1][0] = mfma32(af0, qf[1][s], sa[1][0]);
            sa[1][1] = mfma32(af1, qf[1][s], sa[1][1]);
        }
        __builtin_amdgcn_s_setprio(0);

        u32x4 pfrag[2][4];
        #pragma unroll
        for (int qb = 0; qb < 2; ++qb) {
            // fixed-m softmax: p = 2^S' (Q pre-scaled); 4-way partial sums
            float p0 = 0.f, p1 = 0.f, p2 = 0.f, p3 = 0.f;
            #pragma unroll
            for (int r = 0; r < 16; r += 4) {
                sa[qb][0][r]     = fexp2(sa[qb][0][r]);     p0 += sa[qb][0][r];
                sa[qb][0][r + 1] = fexp2(sa[qb][0][r + 1]); p1 += sa[qb][0][r + 1];
                sa[qb][0][r + 2] = fexp2(sa[qb][0][r + 2]); p2 += sa[qb][0][r + 2];
                sa[qb][0][r + 3] = fexp2(sa[qb][0][r + 3]); p3 += sa[qb][0][r + 3];
                sa[qb][1][r]     = fexp2(sa[qb][1][r]);     p0 += sa[qb][1][r];
                sa[qb][1][r + 1] = fexp2(sa[qb][1][r + 1]); p1 += sa[qb][1][r + 1];
                sa[qb][1][r + 2] = fexp2(sa[qb][1][r + 2]); p2 += sa[qb][1][r + 2];
                sa[qb][1][r + 3] = fexp2(sa[qb][1][r + 3]); p3 += sa[qb][1][r + 3];
            }
            lloc[qb] += (p0 + p1) + (p2 + p3);

            // pack P -> bf16 B-frags: cvt_pk + permlane32_swap (T12)
            #pragma unroll
            for (int t = 0; t < 2; ++t) {
                unsigned pk[8];
                #pragma unroll
                for (int i = 0; i < 8; ++i)
                    pk[i] = cvtpk(sa[qb][t][2 * i], sa[qb][t][2 * i + 1]);
                u32x2 r02 = __builtin_amdgcn_permlane32_swap(pk[0], pk[2], false, false);
                u32x2 r13 = __builtin_amdgcn_permlane32_swap(pk[1], pk[3], false, false);
                u32x2 r46 = __builtin_amdgcn_permlane32_swap(pk[4], pk[6], false, false);
                u32x2 r57 = __builtin_amdgcn_permlane32_swap(pk[5], pk[7], false, false);
                u32x4 fA, fB;
                fA[0] = r02[0]; fA[1] = r13[0]; fA[2] = r02[1]; fA[3] = r13[1];
                fB[0] = r46[0]; fB[1] = r57[0]; fB[2] = r46[1]; fB[3] = r57[1];
                pfrag[qb][2 * t] = fA;
                pfrag[qb][2 * t + 1] = fB;
            }
        }

        // PV: each V-frag read feeds both q-subtiles
        __builtin_amdgcn_s_setprio(1);
        #pragma unroll
        for (int s = 0; s < 4; ++s)
            #pragma unroll
            for (int dt = 0; dt < 2; ++dt) {
                s16x8 vf = frag_read(vbuf, dt * 32 + l31, 2 * s + h);
                o[0][dt] = mfma32(vf, u2s(pfrag[0][s]), o[0][dt]);
                o[1][dt] = mfma32(vf, u2s(pfrag[1][s]), o[1][dt]);
            }
        __builtin_amdgcn_s_setprio(0);

        __syncthreads();   // drain next-tile loads (overlapped) + buffer-reuse barrier
        cur ^= 1;
    }

    // epilogue: scale own branch, exchange br=1 partials via LDS, combine, store
    float alpha = alphap[0];
    float cb = br ? (1.f - alpha) : alpha;
    float inv[2];
    #pragma unroll
    for (int qb = 0; qb < 2; ++qb) {
        float ls = lloc[qb] + __shfl_xor(lloc[qb], 32, 64);
        inv[qb] = cb / ls;
    }

    float* sX = (float*)&sbuf[0][0];   // 32KB of the 48KB LDS, free after last barrier
    if (br) {
        #pragma unroll
        for (int qb = 0; qb < 2; ++qb)
            #pragma unroll
            for (int dt = 0; dt < 2; ++dt)
                #pragma unroll
                for (int g = 0; g < 4; ++g) {
                    int qloc = qg * 64 + qb * 32 + l31;
                    int dsw = (dt * 32 + g * 8 + h * 4) ^ ((l31 & 7) << 3);
                    float4 v4;
                    v4.x = o[qb][dt][4 * g + 0] * inv[qb];
                    v4.y = o[qb][dt][4 * g + 1] * inv[qb];
                    v4.z = o[qb][dt][4 * g + 2] * inv[qb];
                    v4.w = o[qb][dt][4 * g + 3] * inv[qb];
                    *reinterpret_cast<float4*>(sX + qloc * 64 + dsw) = v4;
                }
    }
    __syncthreads();
    if (!br) {
        int b = bh >> 4, hh = bh & 15;
        #pragma unroll
        for (int qb = 0; qb < 2; ++qb) {
            int t = qt0 + qg * 64 + qb * 32 + l31;
            size_t rowbase = ((size_t)(b * TSZ + t)) * CDIM + hh * 64;
            #pragma unroll
            for (int dt = 0; dt < 2; ++dt)
                #pragma unroll
                for (int g = 0; g < 4; ++g) {
                    int qloc = qg * 64 + qb * 32 + l31;
                    int dsw = (dt * 32 + g * 8 + h * 4) ^ ((l31 & 7) << 3);
                    float4 p = *reinterpret_cast<const float4*>(sX + qloc * 64 + dsw);
                    short4 v4;
                    v4.x = f2bf(o[qb][dt][4 * g + 0] * inv[qb] + p.x);
                    v4.y = f2bf(o[qb][dt][4 * g + 1] * inv[qb] + p.y);
                    v4.z = f2bf(o[qb][dt][4 * g + 2] * inv[qb] + p.z);
                    v4.w = f2bf(o[qb][dt][4 * g + 3] * inv[qb] + p.w);
                    *reinterpret_cast<short4*>(aout + rowbase + dt * 32 + g * 8 + h * 4) = v4;
                }
        }
    }
}

// ---------------- host ----------------
extern "C" void kernel_launch(void* const* d_in, const int* in_sizes, int n_in,
                              void* d_out, int out_size, void* d_ws, size_t ws_size,
                              hipStream_t stream)
{
    const float* x     = (const float*)d_in[0];
    const float* WQ    = (const float*)d_in[1];
    const float* WK    = (const float*)d_in[2];
    const float* WV    = (const float*)d_in[3];
    const float* WKp   = (const float*)d_in[4];
    const float* WO    = (const float*)d_in[5];
    const float* alpha = (const float*)d_in[6];
    float* out = (float*)d_out;

    char* ws = (char*)d_ws;
    const size_t MB = 1024 * 1024;
    short* xb   = (short*)(ws + 0);        // 8 MB  x bf16
    short* wqb  = (short*)(ws + 8 * MB);   // 2 MB each
    short* wkb  = (short*)(ws + 10 * MB);
    short* wvb  = (short*)(ws + 12 * MB);
    short* wkpb = (short*)(ws + 14 * MB);
    short* wob  = (short*)(ws + 16 * MB);
    short* qb   = (short*)(ws + 18 * MB);  // 8 MB each, (B,H,T,D)
    short* kb   = (short*)(ws + 26 * MB);
    short* kpb  = (short*)(ws + 34 * MB);
    short* vtb  = (short*)(ws + 42 * MB);  // (B,H,D,T)
    short* anb  = (short*)(ws + 50 * MB);  // attention out, (B,T,C) bf16

    cast_all<<<dim3(1024, 6), 256, 0, stream>>>(x, WQ, WK, WV, WKp, WO,
                                                xb, wqb, wkb, wvb, wkpb, wob);

    gemm4_proj<<<dim3(256, 4), 256, 0, stream>>>(xb, wqb, wkb, wvb, wkpb, qb, kb, vtb, kpb);
    attn_fused<<<dim3(16, 32), 256, 0, stream>>>(qb, kb, kpb, vtb, alpha, anb);
    gemm_final<<<dim3(256), 256, 0, stream>>>(anb, wob, out);
}